// Round 1
// baseline (86.137 us; speedup 1.0000x reference)
//
#include <hip/hip_runtime.h>
#include <math.h>

#define VL 32
#define W  97           // 3*VL + 1
#define NU 50
#define NC 10
#define ND 20

__global__ __launch_bounds__(128) void ffm_kernel(
    const float* __restrict__ user,
    const float* __restrict__ ctx,
    const float* __restrict__ doc,
    float* __restrict__ out)
{
    const int b = blockIdx.x;
    const int j = threadIdx.x;          // 0..127; active for j < 97

    __shared__ float s_su[W];
    __shared__ float s_sc[W];
    __shared__ float s_sd[W];
    __shared__ float s_red[2];

    float su = 0.f, sc = 0.f, sd = 0.f;
    float squ = 0.f, sqc = 0.f, sqd = 0.f;

    if (j < W) {
        const float* up = user + (size_t)b * NU * W + j;
        #pragma unroll
        for (int r = 0; r < NU; ++r) {
            float x = up[(size_t)r * W];
            su  += x;
            squ += x * x;
        }
        const float* cp = ctx + (size_t)b * NC * W + j;
        #pragma unroll
        for (int r = 0; r < NC; ++r) {
            float x = cp[(size_t)r * W];
            sc  += x;
            sqc += x * x;
        }
        const float* dp = doc + (size_t)b * ND * W + j;
        #pragma unroll
        for (int r = 0; r < ND; ++r) {
            float x = dp[(size_t)r * W];
            sd  += x;
            sqd += x * x;
        }
        s_su[j] = su;
        s_sc[j] = sc;
        s_sd[j] = sd;
    }
    __syncthreads();

    // Per-thread partial of z.
    // fm_cross(user[:,0:VL])   = 0.5*(||su[0:VL]||^2   - sum_sq(user cols 0:VL))
    // fm_cross(ctx[:,VL:2VL])  = 0.5*(||sc[VL:2VL]||^2 - sum_sq(ctx cols VL:2VL))
    // fm_cross(doc[:,2VL:3VL]) = 0.5*(||sd[2VL:3VL]||^2- sum_sq(doc cols 2VL:3VL))
    float partial = 0.f;
    if (j < VL)                  partial -= 0.5f * squ;   // user sq cols 0:VL
    else if (j < 2 * VL)         partial -= 0.5f * sqc;   // ctx  sq cols VL:2VL
    else if (j < 3 * VL)         partial -= 0.5f * sqd;   // doc  sq cols 2VL:3VL

    if (j < VL) {
        float a0 = s_su[j];
        float a1 = s_sc[VL + j];
        float a2 = s_sd[2 * VL + j];
        partial += 0.5f * (a0 * a0 + a1 * a1 + a2 * a2);
        partial += s_su[VL + j]     * s_sc[j];            // dot(su[VL:2VL],  sc[0:VL])
        partial += s_su[2 * VL + j] * s_sd[j];            // dot(su[2VL:3VL], sd[0:VL])
        partial += s_sc[2 * VL + j] * s_sd[VL + j];       // dot(sc[2VL:3VL], sd[VL:2VL])
    }
    if (j == 3 * VL)
        partial += s_su[j] + s_sc[j] + s_sd[j];           // linear/bias column

    // Reduce across 128 threads: wave64 shuffle, then 2-entry LDS.
    #pragma unroll
    for (int off = 32; off > 0; off >>= 1)
        partial += __shfl_down(partial, off, 64);
    if ((j & 63) == 0)
        s_red[j >> 6] = partial;
    __syncthreads();
    if (j == 0) {
        float z = s_red[0] + s_red[1];
        out[b] = 1.0f / (1.0f + expf(-z));
    }
}

extern "C" void kernel_launch(void* const* d_in, const int* in_sizes, int n_in,
                              void* d_out, int out_size, void* d_ws, size_t ws_size,
                              hipStream_t stream) {
    const float* user = (const float*)d_in[0];
    const float* ctx  = (const float*)d_in[1];
    const float* doc  = (const float*)d_in[2];
    float* out = (float*)d_out;

    const int B = out_size;   // 16384 batch rows, one per output element
    ffm_kernel<<<B, 128, 0, stream>>>(user, ctx, doc, out);
}